// Round 4
// baseline (472.011 us; speedup 1.0000x reference)
//
#include <hip/hip_runtime.h>
#include <hip/hip_bf16.h>
#include <cstdint>

#define N_NODES 50000
#define N_EDGES 800000

// ---------------------------------------------------------------------------
// feat = X @ W  and el/er = per-head attention dots.
// 256 threads = 4 waves; each wave computes 8 rows x DOUT cols (CPT cols/lane).
// X rows staged in LDS (read as wave-uniform float4 broadcasts); W streamed
// from L2 with a register ping-pong double buffer.
template<int DIN, int DOUT, int F>
__global__ __launch_bounds__(256) void gemm_attn(
    const float* __restrict__ X, const float* __restrict__ W,
    const float* __restrict__ al, const float* __restrict__ ar,
    float* __restrict__ feat, float* __restrict__ el, float* __restrict__ er, int N)
{
    constexpr int RPT = 8;           // rows per wave
    constexpr int ROWS = 32;         // rows per block
    constexpr int CPT = DOUT / 64;   // cols per lane (2 for 128, 1 for 64)
    constexpr int H = DOUT / F;
    constexpr int NK = DIN / 4;      // k-steps of 4
    __shared__ float xs[ROWS][DIN];

    const int tid = threadIdx.x;
    const int wid = tid >> 6;
    const int lane = tid & 63;
    const int row0 = blockIdx.x * ROWS;

    // cooperative stage: 32 rows of X, float4 coalesced
    for (int idx = tid; idx < ROWS * (DIN / 4); idx += 256) {
        int r = idx / (DIN / 4), k4 = idx % (DIN / 4);
        int row = row0 + r;
        float4 v = (row < N) ? *reinterpret_cast<const float4*>(&X[(size_t)row * DIN + k4 * 4])
                             : make_float4(0.f, 0.f, 0.f, 0.f);
        *reinterpret_cast<float4*>(&xs[r][k4 * 4]) = v;
    }
    __syncthreads();

    float acc[CPT][RPT];
#pragma unroll
    for (int c = 0; c < CPT; ++c)
#pragma unroll
        for (int r = 0; r < RPT; ++r) acc[c][r] = 0.f;

    const float* Wp = W + lane;

    auto loadW = [&](float (&wb)[CPT][4], int ks) {
#pragma unroll
        for (int c = 0; c < CPT; ++c)
#pragma unroll
            for (int kk = 0; kk < 4; ++kk)
                wb[c][kk] = Wp[(size_t)(ks * 4 + kk) * DOUT + c * 64];
    };
    auto doFMA = [&](float (&wb)[CPT][4], int ks) {
#pragma unroll
        for (int r = 0; r < RPT; ++r) {
            const float4 xv = *reinterpret_cast<const float4*>(&xs[wid * RPT + r][ks * 4]);
#pragma unroll
            for (int c = 0; c < CPT; ++c) {
                acc[c][r] = fmaf(xv.x, wb[c][0], acc[c][r]);
                acc[c][r] = fmaf(xv.y, wb[c][1], acc[c][r]);
                acc[c][r] = fmaf(xv.z, wb[c][2], acc[c][r]);
                acc[c][r] = fmaf(xv.w, wb[c][3], acc[c][r]);
            }
        }
    };

    float wA[CPT][4], wB[CPT][4];
    loadW(wA, 0);
#pragma unroll 2
    for (int ks = 0; ks < NK; ks += 2) {           // NK is even
        loadW(wB, ks + 1);
        doFMA(wA, ks);
        if (ks + 2 < NK) loadW(wA, ks + 2);
        doFMA(wB, ks + 1);
    }

    float alv[CPT], arv[CPT];
#pragma unroll
    for (int c = 0; c < CPT; ++c) { alv[c] = al[lane + c * 64]; arv[c] = ar[lane + c * 64]; }

#pragma unroll
    for (int r = 0; r < RPT; ++r) {
        int row = row0 + wid * RPT + r;
#pragma unroll
        for (int c = 0; c < CPT; ++c) {
            float pl = acc[c][r] * alv[c];
            float pr = acc[c][r] * arv[c];
#pragma unroll
            for (int off = 1; off < F; off <<= 1) {
                pl += __shfl_xor(pl, off);
                pr += __shfl_xor(pr, off);
            }
            if (row < N) {
                feat[(size_t)row * DOUT + lane + c * 64] = acc[c][r];
                if ((lane & (F - 1)) == 0) {
                    int head = (lane + c * 64) / F;
                    el[(size_t)row * H + head] = pl;
                    er[(size_t)row * H + head] = pr;
                }
            }
        }
    }
}

// ---------------------------------------------------------------------------
// CSR build (dst-sorted), shared by all 3 layers
__global__ void zero_ints(int* __restrict__ a, int n)
{
    int i = blockIdx.x * blockDim.x + threadIdx.x;
    if (i < n) a[i] = 0;
}

__global__ void hist_deg(const int* __restrict__ dst, int* __restrict__ deg)
{
    int e = blockIdx.x * blockDim.x + threadIdx.x;
    if (e < N_EDGES) atomicAdd(&deg[dst[e]], 1);
}

// single block, 1024 threads: exclusive scan of deg[0..n) -> offs[0..n]
__global__ __launch_bounds__(1024) void scan_offsets(
    const int* __restrict__ deg, int* __restrict__ offs, int n)
{
    __shared__ int wtot[16], wincl[16];
    __shared__ int carry_s;
    const int tid = threadIdx.x;
    const int lane = tid & 63, wid = tid >> 6;
    if (tid == 0) carry_s = 0;
    __syncthreads();
    for (int base = 0; base < n; base += 1024) {
        int i = base + tid;
        int v = (i < n) ? deg[i] : 0;
        int x = v;
#pragma unroll
        for (int off = 1; off < 64; off <<= 1) {
            int t = __shfl_up(x, off);
            if (lane >= off) x += t;
        }
        if (lane == 63) wtot[wid] = x;
        __syncthreads();
        if (tid < 16) {
            int wx = wtot[tid];
#pragma unroll
            for (int off = 1; off < 16; off <<= 1) {
                int t = __shfl_up(wx, off);
                if (tid >= off) wx += t;
            }
            wincl[tid] = wx;
        }
        __syncthreads();
        int waveExcl = (wid == 0) ? 0 : wincl[wid - 1];
        if (i < n) offs[i] = carry_s + waveExcl + (x - v);
        int total = wincl[15];
        __syncthreads();
        if (tid == 0) carry_s += total;
        __syncthreads();
    }
    if (threadIdx.x == 0) offs[n] = carry_s;
}

__global__ void build_csr(const int* __restrict__ src, const int* __restrict__ dst,
                          const int* __restrict__ offs, int* __restrict__ cursor,
                          int* __restrict__ csr_src)
{
    int e = blockIdx.x * blockDim.x + threadIdx.x;
    if (e >= N_EDGES) return;
    int d = dst[e];
    int p = offs[d] + atomicAdd(&cursor[d], 1);
    csr_src[p] = src[e];
}

// ---------------------------------------------------------------------------
// Fused flash-style softmax + aggregation per dst node. One wave per node.
template<int H, int F, bool ACT>
__global__ __launch_bounds__(256) void node_flash_agg(
    const int* __restrict__ offs, const int* __restrict__ csr_src,
    const float* __restrict__ el, const float* __restrict__ er,
    const float* __restrict__ feat, const float* __restrict__ bias,
    float* __restrict__ out, int N)
{
    constexpr int D = H * F;
    constexpr int CPT = D / 64;     // components per lane (2 or 1)
    constexpr int EPC = 64 / H;     // edges per chunk (8 or 64)
    constexpr int SB = 8;           // feat-load batch depth

    const int wid = threadIdx.x >> 6;
    const int lane = threadIdx.x & 63;
    const int n = blockIdx.x * 4 + wid;
    if (n >= N) return;

    const int beg = offs[n];
    const int deg = offs[n + 1] - beg;

    const int h = lane % H;
    const int esub = lane / H;
    const float erd = er[(size_t)n * H + h];

    float m_run = -1e30f, s_run = 0.f;
    float acc[CPT];
#pragma unroll
    for (int c = 0; c < CPT; ++c) acc[c] = 0.f;

    for (int base = 0; base < deg; base += EPC) {
        int ei = base + esub;
        int s_mine = csr_src[beg + min(ei, deg - 1)];   // clamped for padding
        float v = el[(size_t)s_mine * H + h] + erd;
        v = (v > 0.f) ? v : 0.2f * v;                   // leaky_relu 0.2
        float logit = (ei < deg) ? v : -1e30f;

        float cmax = logit;
#pragma unroll
        for (int off = H; off < 64; off <<= 1)
            cmax = fmaxf(cmax, __shfl_xor(cmax, off));
        float nm = fmaxf(m_run, cmax);
        float scale = __expf(m_run - nm);               // 0 on first chunk
        float ex = __expf(logit - nm);                  // 0 for padded lanes
        float csum = ex;
#pragma unroll
        for (int off = H; off < 64; off <<= 1)
            csum += __shfl_xor(csum, off);
        s_run = s_run * scale + csum;
        m_run = nm;

#pragma unroll
        for (int c = 0; c < CPT; ++c)
            acc[c] *= __shfl(scale, (lane + c * 64) / F);

        int active = min(EPC, deg - base);
        for (int g = 0; g < active; g += SB) {
            float fv[SB][CPT];
#pragma unroll
            for (int ii = 0; ii < SB; ++ii) {
                int sl = __shfl(s_mine, (g + ii) * H);  // edge g+ii src row
#pragma unroll
                for (int c = 0; c < CPT; ++c)
                    fv[ii][c] = feat[(size_t)sl * D + lane + c * 64];
            }
#pragma unroll
            for (int ii = 0; ii < SB; ++ii)
#pragma unroll
                for (int c = 0; c < CPT; ++c) {
                    float exb = __shfl(ex, (g + ii) * H + (lane + c * 64) / F);
                    acc[c] = fmaf(fv[ii][c], exb, acc[c]);
                }
        }
    }

    const float inv = (s_run > 0.f) ? 1.f / s_run : 0.f;
#pragma unroll
    for (int c = 0; c < CPT; ++c) {
        int comp = lane + c * 64;
        float v = acc[c] * __shfl(inv, comp / F) + bias[comp];
        if (ACT) v = (v > 0.f) ? v : expm1f(v);         // ELU alpha=1
        out[(size_t)n * D + comp] = v;
    }
}

// ---------------------------------------------------------------------------
extern "C" void kernel_launch(void* const* d_in, const int* in_sizes, int n_in,
                              void* d_out, int out_size, void* d_ws, size_t ws_size,
                              hipStream_t stream)
{
    const float* x   = (const float*)d_in[0];
    const int*   src = (const int*)d_in[1];
    const int*   dst = (const int*)d_in[2];
    const float* W0  = (const float*)d_in[3];
    const float* al0 = (const float*)d_in[4];
    const float* ar0 = (const float*)d_in[5];
    const float* b0  = (const float*)d_in[6];
    const float* W1  = (const float*)d_in[7];
    const float* al1 = (const float*)d_in[8];
    const float* ar1 = (const float*)d_in[9];
    const float* b1  = (const float*)d_in[10];
    const float* W2  = (const float*)d_in[11];
    const float* al2 = (const float*)d_in[12];
    const float* ar2 = (const float*)d_in[13];
    const float* b2  = (const float*)d_in[14];
    float* out = (float*)d_out;

    const int N = N_NODES, E = N_EDGES;

    float* ws   = (float*)d_ws;
    float* feat = ws;                         // N*128
    float* hbuf = feat + (size_t)N * 128;     // N*128
    float* elb  = hbuf + (size_t)N * 128;     // N*8
    float* erb  = elb + (size_t)N * 8;        // N*8
    int* ibase   = (int*)(erb + (size_t)N * 8);
    int* deg     = ibase;                     // N
    int* cursor  = deg + N;                   // N
    int* offs    = cursor + N;                // N+1
    int* csr_src = offs + N + 1;              // E

    const int TB = 256;
    const int gb_rows32 = (N + 31) / 32;
    const int gb_edges  = (E + TB - 1) / TB;
    const int gb_nodes  = (N + 3) / 4;

    // ---- CSR build (shared by all 3 layers) ----
    zero_ints<<<(2 * N + TB - 1) / TB, TB, 0, stream>>>(deg, 2 * N);  // deg+cursor
    hist_deg<<<gb_edges, TB, 0, stream>>>(dst, deg);
    scan_offsets<<<1, 1024, 0, stream>>>(deg, offs, N);
    build_csr<<<gb_edges, TB, 0, stream>>>(src, dst, offs, cursor, csr_src);

    // ---- layer 0: 256 -> 8 heads x 16, ELU ----
    gemm_attn<256, 128, 16><<<gb_rows32, 256, 0, stream>>>(x, W0, al0, ar0, feat, elb, erb, N);
    node_flash_agg<8, 16, true><<<gb_nodes, 256, 0, stream>>>(
        offs, csr_src, elb, erb, feat, b0, hbuf, N);

    // ---- layer 1: 128 -> 8 heads x 16, ELU ----
    gemm_attn<128, 128, 16><<<gb_rows32, 256, 0, stream>>>(hbuf, W1, al1, ar1, feat, elb, erb, N);
    node_flash_agg<8, 16, true><<<gb_nodes, 256, 0, stream>>>(
        offs, csr_src, elb, erb, feat, b1, hbuf, N);

    // ---- layer 2: 128 -> 1 head x 64, no act ----
    gemm_attn<128, 64, 64><<<gb_rows32, 256, 0, stream>>>(hbuf, W2, al2, ar2, feat, elb, erb, N);
    node_flash_agg<1, 64, false><<<gb_nodes, 256, 0, stream>>>(
        offs, csr_src, elb, erb, feat, b2, out, N);
}